// Round 1
// baseline (2039.031 us; speedup 1.0000x reference)
//
#include <hip/hip_runtime.h>
#include <hip/hip_bf16.h>

// RNN: S=128, B=64, E=512, H=1024, V=10000, L=2.  M = S*B = 8192.
// Plan: prep(convert weights->bf16, gather emb) -> GEMM X0 -> rec layer0
//       -> GEMM X1 -> rec layer1 -> GEMM logits.
// All GEMMs: bf16 MFMA 16x16x32, f32 accumulate, 128x128 tile (m97 structure).

typedef unsigned short u16;
typedef unsigned int   u32;
typedef unsigned long long u64;
typedef __bf16 bf16x8 __attribute__((ext_vector_type(8)));
typedef float  f32x4  __attribute__((ext_vector_type(4)));

__device__ __forceinline__ u16 f2b(float f) {
  __hip_bfloat16 h = __float2bfloat16(f);
  return __builtin_bit_cast(u16, h);
}
__device__ __forceinline__ float b2f(u16 u) {
  return __bfloat162float(__builtin_bit_cast(__hip_bfloat16, u));
}

__device__ __forceinline__ void gload16(const void* g, void* lds) {
  __builtin_amdgcn_global_load_lds(
      (const __attribute__((address_space(1))) u32*)g,
      (__attribute__((address_space(3))) u32*)lds, 16, 0, 0);
}

// ---------------------------------------------------------------- prep
__device__ __forceinline__ void cvt4(const float* __restrict__ s,
                                     u16* __restrict__ d, int n4,
                                     int gid, int stride) {
  for (int i = gid; i < n4; i += stride) {
    float4 f = ((const float4*)s)[i];
    ushort4 u;
    u.x = f2b(f.x); u.y = f2b(f.y); u.z = f2b(f.z); u.w = f2b(f.w);
    ((ushort4*)d)[i] = u;
  }
}

__global__ __launch_bounds__(256) void prep_kernel(
    const int* __restrict__ inputs, const float* __restrict__ hidden,
    const float* __restrict__ emb,
    const float* __restrict__ Wx0, const float* __restrict__ Wh0,
    const float* __restrict__ Wx1, const float* __restrict__ Wh1,
    const float* __restrict__ Wout,
    u16* Wx0b, u16* Wh0b, u16* Wx1b, u16* Wh1b, u16* Woutb,
    u16* A0b, u16* hA0, u16* hA1, int* counters) {
  int gid = blockIdx.x * 256 + threadIdx.x;
  int stride = gridDim.x * 256;
  if (gid < 64) counters[gid] = 0;
  cvt4(Wx0, Wx0b, 1024 * 512 / 4, gid, stride);
  cvt4(Wh0, Wh0b, 1024 * 1024 / 4, gid, stride);
  cvt4(Wx1, Wx1b, 1024 * 1024 / 4, gid, stride);
  cvt4(Wh1, Wh1b, 1024 * 1024 / 4, gid, stride);
  cvt4(Wout, Woutb, 10000 * 1024 / 4, gid, stride);
  cvt4(hidden, hA0, 65536 / 4, gid, stride);
  cvt4(hidden + 65536, hA1, 65536 / 4, gid, stride);
  // embedding gather -> bf16 A0 (8192 x 512)
  for (int i = gid; i < 8192 * 128; i += stride) {
    int m = i >> 7, e4 = i & 127;
    int r = inputs[m];
    float4 f = ((const float4*)(emb + (size_t)r * 512))[e4];
    ushort4 u;
    u.x = f2b(f.x); u.y = f2b(f.y); u.z = f2b(f.z); u.w = f2b(f.w);
    ((ushort4*)A0b)[i] = u;
  }
}

// ---------------------------------------------------------------- GEMM
// C[M,N] = A[M,K](bf16) @ B[N,K](bf16)^T + bias[N], 128x128 tile, 4 waves.
template <bool BF16OUT>
__global__ __launch_bounds__(256) void gemm_bt(
    const u16* __restrict__ A, const u16* __restrict__ Bm,
    const float* __restrict__ bias, void* __restrict__ Cout,
    int M, int N, int K) {
  const int tid = threadIdx.x;
  const int l = tid & 63;
  const int wv = tid >> 6;
  const int MT = M >> 7;
  const int bm = (int)blockIdx.x % MT;
  const int bn = (int)blockIdx.x / MT;
  const int m0 = bm * 128, n0 = bn * 128;

  __shared__ u16 As[128 * 32];
  __shared__ u16 Bs[128 * 32];

  // staging: flat byte offset within 8KB tile = (j*4+wv)*1024 + l*16
  const int fa0 = wv * 1024 + l * 16;
  const int fa1 = (4 + wv) * 1024 + l * 16;
  const int rowA0 = fa0 >> 6, kO0 = (fa0 & 63) >> 1;
  const int rowA1 = fa1 >> 6, kO1 = (fa1 & 63) >> 1;
  const u16* gA0 = A + (size_t)(m0 + rowA0) * K + kO0;
  const u16* gA1 = A + (size_t)(m0 + rowA1) * K + kO1;
  int rB0 = n0 + rowA0; if (rB0 >= N) rB0 = N - 1;   // clamp (finite data)
  int rB1 = n0 + rowA1; if (rB1 >= N) rB1 = N - 1;
  const u16* gB0 = Bm + (size_t)rB0 * K + kO0;
  const u16* gB1 = Bm + (size_t)rB1 * K + kO1;
  u16* lA0 = As + wv * 512;
  u16* lA1 = As + (4 + wv) * 512;
  u16* lB0 = Bs + wv * 512;
  u16* lB1 = Bs + (4 + wv) * 512;

  const int wm = wv >> 1, wn = wv & 1;
  const u16* pA = As + (wm * 64 + (l & 15)) * 32 + (l >> 4) * 8;
  const u16* pB = Bs + (wn * 64 + (l & 15)) * 32 + (l >> 4) * 8;

  f32x4 acc[4][4] = {};

  for (int k0 = 0; k0 < K; k0 += 32) {
    __syncthreads();
    gload16(gA0 + k0, lA0);
    gload16(gA1 + k0, lA1);
    gload16(gB0 + k0, lB0);
    gload16(gB1 + k0, lB1);
    asm volatile("s_waitcnt vmcnt(0)" ::: "memory");
    __syncthreads();
    bf16x8 a[4], b[4];
#pragma unroll
    for (int i = 0; i < 4; ++i) a[i] = *(const bf16x8*)(pA + i * 512);
#pragma unroll
    for (int j = 0; j < 4; ++j) b[j] = *(const bf16x8*)(pB + j * 512);
#pragma unroll
    for (int i = 0; i < 4; ++i)
#pragma unroll
      for (int j = 0; j < 4; ++j)
        acc[i][j] = __builtin_amdgcn_mfma_f32_16x16x32_bf16(a[i], b[j],
                                                            acc[i][j], 0, 0, 0);
  }

  // epilogue: C[row=(l>>4)*4+r][col=l&15] per fragment
#pragma unroll
  for (int j = 0; j < 4; ++j) {
    int cn = n0 + wn * 64 + j * 16 + (l & 15);
    if (cn >= N) continue;
    float bv = bias[cn];
#pragma unroll
    for (int i = 0; i < 4; ++i) {
      int rmb = m0 + wm * 64 + i * 16 + ((l >> 4) << 2);
#pragma unroll
      for (int r = 0; r < 4; ++r) {
        float v = acc[i][j][r] + bv;
        if (BF16OUT)
          ((u16*)Cout)[(size_t)(rmb + r) * N + cn] = f2b(v);
        else
          ((float*)Cout)[(size_t)(rmb + r) * N + cn] = v;
      }
    }
  }
}

// ------------------------------------------------------------ recurrence
// h_t = tanh(X[t] + h_{t-1} @ Wh^T).  128 WGs = 4 batch-groups(16) x 32
// col-chunks(32).  4 waves/WG: (col-half cw) x (K-half kw).  Per-bg atomic
// barrier (32 arrivals).  h state ping-pong, agent-scope (cache-bypass)
// loads/stores so Wh stays L2-resident.
__global__ __launch_bounds__(256) void rnn_rec(
    const u16* __restrict__ X, const u16* __restrict__ Wh,
    u16* __restrict__ Hout, u16* __restrict__ h0buf, u16* __restrict__ h1buf,
    float* __restrict__ hfin, int* __restrict__ cnt) {
  const int wg = blockIdx.x;
  const int bg = wg & 3;
  const int cc = wg >> 2;
  const int tid = threadIdx.x;
  const int l = tid & 63;
  const int wv = tid >> 6;
  const int cw = wv & 1;
  const int kw = wv >> 1;
  const int col = cc * 32 + cw * 16 + (l & 15);
  const int arow = bg * 16 + (l & 15);
  const int kbase = kw * 512 + ((l >> 4) * 8);
  const u16* wp = Wh + (size_t)col * 1024 + kbase;
  __shared__ float red[2][16][16];
  __shared__ u16 htile[16][32];
  int* counter = cnt + bg;

  for (int t = 0; t < 128; ++t) {
    const u16* hsrc = (t & 1) ? h1buf : h0buf;
    u16* hdst = (t & 1) ? h0buf : h1buf;
    const u64* ap = (const u64*)(hsrc + (size_t)arow * 1024 + kbase);
    f32x4 acc = {0.f, 0.f, 0.f, 0.f};
#pragma unroll
    for (int kt = 0; kt < 16; ++kt) {
      u64 alo = __hip_atomic_load(ap + kt * 8, __ATOMIC_RELAXED,
                                  __HIP_MEMORY_SCOPE_AGENT);
      u64 ahi = __hip_atomic_load(ap + kt * 8 + 1, __ATOMIC_RELAXED,
                                  __HIP_MEMORY_SCOPE_AGENT);
      union { u64 q[2]; bf16x8 v; } ua;
      ua.q[0] = alo; ua.q[1] = ahi;
      bf16x8 bv = *(const bf16x8*)(wp + kt * 32);
      acc = __builtin_amdgcn_mfma_f32_16x16x32_bf16(ua.v, bv, acc, 0, 0, 0);
    }
    if (kw == 1) {
#pragma unroll
      for (int r = 0; r < 4; ++r) red[cw][(l >> 4) * 4 + r][l & 15] = acc[r];
    }
    __syncthreads();
    if (kw == 0) {
#pragma unroll
      for (int r = 0; r < 4; ++r) {
        int br = (l >> 4) * 4 + r;
        int bat = bg * 16 + br;
        float v = acc[r] + red[cw][br][l & 15];
        v += b2f(X[(size_t)(t * 64 + bat) * 1024 + col]);
        v = tanhf(v);
        u16 hb = f2b(v);
        Hout[(size_t)(t * 64 + bat) * 1024 + col] = hb;
        htile[br][cw * 16 + (l & 15)] = hb;
        if (t == 127) hfin[bat * 1024 + col] = v;
      }
    }
    __syncthreads();
    if (t == 127) break;
    if (tid < 128) {  // publish h_next: 16 rows x 64B, agent-scope 8B stores
      int row = tid >> 3, seg = tid & 7;
      u64 v = ((const u64*)htile)[tid];
      u64* dp = (u64*)(hdst + (size_t)(bg * 16 + row) * 1024 + cc * 32);
      __hip_atomic_store(dp + seg, v, __ATOMIC_RELAXED,
                         __HIP_MEMORY_SCOPE_AGENT);
    }
    __syncthreads();  // drains vmcnt per wave -> stores at coherence point
    if (tid == 0) {
      __hip_atomic_fetch_add(counter, 1, __ATOMIC_RELAXED,
                             __HIP_MEMORY_SCOPE_AGENT);
      int target = (t + 1) * 32;
      while (__hip_atomic_load(counter, __ATOMIC_RELAXED,
                               __HIP_MEMORY_SCOPE_AGENT) < target) {
        __builtin_amdgcn_s_sleep(1);
      }
    }
    __syncthreads();
  }
}

// ---------------------------------------------------------------- launch
extern "C" void kernel_launch(void* const* d_in, const int* in_sizes, int n_in,
                              void* d_out, int out_size, void* d_ws,
                              size_t ws_size, hipStream_t stream) {
  const int*   inputs = (const int*)d_in[0];
  const float* hidden = (const float*)d_in[1];
  const float* emb    = (const float*)d_in[2];
  const float* Wx0    = (const float*)d_in[3];
  const float* Wh0    = (const float*)d_in[4];
  const float* bh0    = (const float*)d_in[5];
  const float* Wx1    = (const float*)d_in[6];
  const float* Wh1    = (const float*)d_in[7];
  const float* bh1    = (const float*)d_in[8];
  const float* Wout   = (const float*)d_in[9];
  const float* bout   = (const float*)d_in[10];
  float* out = (float*)d_out;

  if (ws_size < (size_t)104 * 1024 * 1024) return;  // need ~99MB scratch

  char* w = (char*)d_ws;
  u16* Wx0b  = (u16*)w; w += 1048576;
  u16* Wh0b  = (u16*)w; w += 2097152;
  u16* Wx1b  = (u16*)w; w += 2097152;
  u16* Wh1b  = (u16*)w; w += 2097152;
  u16* Woutb = (u16*)w; w += 20480000;
  u16* A0b   = (u16*)w; w += 8388608;
  u16* X0b   = (u16*)w; w += 16777216;
  u16* X1b   = (u16*)w; w += 16777216;
  u16* H0b   = (u16*)w; w += 16777216;
  u16* H1b   = (u16*)w; w += 16777216;
  u16* hA0   = (u16*)w; w += 131072;
  u16* hB0   = (u16*)w; w += 131072;
  u16* hA1   = (u16*)w; w += 131072;
  u16* hB1   = (u16*)w; w += 131072;
  int* counters = (int*)w;

  float* hfin0 = out + 81920000;          // hidden_final layer 0
  float* hfin1 = out + 81920000 + 65536;  // hidden_final layer 1

  prep_kernel<<<2048, 256, 0, stream>>>(inputs, hidden, emb, Wx0, Wh0, Wx1,
                                        Wh1, Wout, Wx0b, Wh0b, Wx1b, Wh1b,
                                        Woutb, A0b, hA0, hA1, counters);
  // X0 = emb_gathered @ Wx0^T + bh0   (8192 x 1024, K=512)
  gemm_bt<true><<<512, 256, 0, stream>>>(A0b, Wx0b, bh0, X0b, 8192, 1024, 512);
  // layer 0 recurrence
  rnn_rec<<<128, 256, 0, stream>>>(X0b, Wh0b, H0b, hA0, hB0, hfin0, counters);
  // X1 = H0 @ Wx1^T + bh1   (8192 x 1024, K=1024)
  gemm_bt<true><<<512, 256, 0, stream>>>(H0b, Wx1b, bh1, X1b, 8192, 1024, 1024);
  // layer 1 recurrence
  rnn_rec<<<128, 256, 0, stream>>>(X1b, Wh1b, H1b, hA1, hB1, hfin1,
                                   counters + 4);
  // logits = H1 @ Wout^T + bout   (8192 x 10000, K=1024)
  gemm_bt<false><<<64 * 79, 256, 0, stream>>>(H1b, Woutb, bout, out, 8192,
                                              10000, 1024);
}